// Round 14
// baseline (725.772 us; speedup 1.0000x reference)
//
#include <hip/hip_runtime.h>

#define BB 2
#define NN 16384
#define MM 4096
#define KK 16
#define CQ 64
#define GEOC 18
#define EPSV 1e-5
#define SPL 8   // M-split per query for kNN phase A

// exact numpy-order fp32 squared distance; contract(off) so bits are identical
// in every kernel that evaluates it.
__device__ __forceinline__ float dist2f(float sa, float ax, float ay, float az, float4 p) {
#pragma clang fp contract(off)
  return (sa + p.w) - 2.0f * ((ax * p.x + ay * p.y) + az * p.z);
}

__device__ __forceinline__ void ce(float& a, float& b) {
  float lo = fminf(a, b), hi = fmaxf(a, b); a = lo; b = hi;
}
__device__ __forceinline__ void sort8(float* v) {
  ce(v[0],v[1]); ce(v[2],v[3]); ce(v[4],v[5]); ce(v[6],v[7]);
  ce(v[0],v[2]); ce(v[1],v[3]); ce(v[4],v[6]); ce(v[5],v[7]);
  ce(v[1],v[2]); ce(v[5],v[6]);
  ce(v[0],v[4]); ce(v[1],v[5]); ce(v[2],v[6]); ce(v[3],v[7]);
  ce(v[2],v[4]); ce(v[3],v[5]);
  ce(v[1],v[2]); ce(v[3],v[4]); ce(v[5],v[6]);
}
__device__ __forceinline__ void bitonic16(float* v) {
#pragma unroll
  for (int i = 0; i < 8; i++) ce(v[i], v[i + 8]);
  ce(v[0],v[4]); ce(v[1],v[5]); ce(v[2],v[6]); ce(v[3],v[7]);
  ce(v[8],v[12]); ce(v[9],v[13]); ce(v[10],v[14]); ce(v[11],v[15]);
  ce(v[0],v[2]); ce(v[1],v[3]); ce(v[4],v[6]); ce(v[5],v[7]);
  ce(v[8],v[10]); ce(v[9],v[11]); ce(v[12],v[14]); ce(v[13],v[15]);
  ce(v[0],v[1]); ce(v[2],v[3]); ce(v[4],v[5]); ce(v[6],v[7]);
  ce(v[8],v[9]); ce(v[10],v[11]); ce(v[12],v[13]); ce(v[14],v[15]);
}
__device__ __forceinline__ void merge16_8(float* dv, const float* t) {
  dv[8]  = fminf(dv[8],  t[7]);  dv[9]  = fminf(dv[9],  t[6]);
  dv[10] = fminf(dv[10], t[5]);  dv[11] = fminf(dv[11], t[4]);
  dv[12] = fminf(dv[12], t[3]);  dv[13] = fminf(dv[13], t[2]);
  dv[14] = fminf(dv[14], t[1]);  dv[15] = fminf(dv[15], t[0]);
  bitonic16(dv);
}

// ------- init: transpose lr points/values, effective Qp weights R/rb, zero stats header -------
__global__ __launch_bounds__(256) void init_k(const float* __restrict__ xyz,
    const float* __restrict__ val, float* __restrict__ xyzT, float* __restrict__ valT,
    const float* __restrict__ qw, const float* __restrict__ qb, const float* __restrict__ w2,
    float* __restrict__ R, float* __restrict__ rb, int* __restrict__ hdr)
{
#pragma clang fp contract(off)
  if (blockIdx.x < 32) {
    int i = blockIdx.x * 256 + threadIdx.x;  // B*M
    int b = i / MM, m = i % MM;
    float x = xyz[(b * 3 + 0) * MM + m];
    float y = xyz[(b * 3 + 1) * MM + m];
    float z = xyz[(b * 3 + 2) * MM + m];
    float sb = (x * x + y * y) + z * z;      // exact numpy order
    ((float4*)xyzT)[i] = make_float4(x, y, z, sb);
    float v0 = val[((size_t)b * 6 + 0) * MM + m];
    float v1 = val[((size_t)b * 6 + 1) * MM + m];
    float v2 = val[((size_t)b * 6 + 2) * MM + m];
    float v3 = val[((size_t)b * 6 + 3) * MM + m];
    float v4 = val[((size_t)b * 6 + 4) * MM + m];
    float v5 = val[((size_t)b * 6 + 5) * MM + m];
    ((float4*)valT)[2 * i]     = make_float4(v0, v1, v2, v3);
    ((float4*)valT)[2 * i + 1] = make_float4(v4, v5, 0.f, 0.f);
  } else {
    int t = threadIdx.x;
    for (int wd = t; wd < 1376; wd += 256) hdr[wd] = 0;   // ctrs + sums region
#pragma unroll
    for (int e = t * 16; e < t * 16 + 16; e++) {          // R = rp_w2^T * q_w
      int o = e >> 6, i = e & 63;
      float acc = 0.f;
#pragma unroll
      for (int p = 0; p < CQ; p++) acc = fmaf(w2[p * CQ + o], qw[p * CQ + i], acc);
      R[e] = acc;
    }
    if (t < CQ) {
      float a = 0.f;
#pragma unroll
      for (int p = 0; p < CQ; p++) a = fmaf(w2[p * CQ + t], qb[p], a);
      rb[t] = a;
    }
  }
}

// ---- knnA body: per-(query, residue) top-16 values + in-wave butterfly merge -> theta ----
__device__ __forceinline__ void knnA_body(int tid, const float* __restrict__ xyz_hr,
    const float* __restrict__ xyzT, float* __restrict__ theta)
{
#pragma clang fp contract(off)
  int s = tid & (SPL - 1);
  int qi = tid / SPL;                        // b*NN + n
  int b = qi / NN, n = qi % NN;
  float ax = xyz_hr[(b * 3 + 0) * NN + n];
  float ay = xyz_hr[(b * 3 + 1) * NN + n];
  float az = xyz_hr[(b * 3 + 2) * NN + n];
  float sa = (ax * ax + ay * ay) + az * az;
  const float4* __restrict__ Ps = ((const float4*)xyzT) + (size_t)b * MM + s;
  float dv[16];
#pragma unroll
  for (int j = 0; j < 16; j++) dv[j] = 3.4e38f;
  for (int j = 0; j < MM / SPL; j += 8) {
    float t[8];
#pragma unroll
    for (int u = 0; u < 8; u++) {
      float4 p = Ps[(size_t)(j + u) * SPL];
      t[u] = dist2f(sa, ax, ay, az, p);
    }
    sort8(t);
    merge16_8(dv, t);
  }
#pragma unroll
  for (int mask = 1; mask <= 4; mask <<= 1) {
    float c[16];
#pragma unroll
    for (int j = 0; j < 16; j++) c[j] = __shfl_xor(dv[15 - j], mask);
#pragma unroll
    for (int j = 0; j < 16; j++) dv[j] = fminf(dv[j], c[j]);
    bitonic16(dv);
  }
  if (s == 0) theta[qi] = dv[15];
}

// ---- fused hr+lr conv (COUT=64, 16 out/thread, CHANNEL-CHUNKED: no spills) + BN stats ----
// Chunking keeps only xr[16]+acc[16] live; per-output sum order stays c=0..CIN-1 ascending
// -> outputs bit-identical to the unchunked version.
template<int CIN>
__device__ __forceinline__ void convstats_hl(int cbid,
    const float* __restrict__ xh, const float* __restrict__ xl,
    const float* __restrict__ W, const float* __restrict__ bias,
    const float* __restrict__ ABh_in, const float* __restrict__ ABl_in,
    float* __restrict__ yh, float* __restrict__ yl,
    double* __restrict__ sums, int* __restrict__ ctr,
    const float* __restrict__ gw, const float* __restrict__ btw,
    float* __restrict__ ABh_out, float* __restrict__ ABl_out,
    float* red, int* plastf)
{
  bool ish = cbid < 512;
  const float* x = ish ? xh : xl;
  const float* ABi = ish ? ABh_in : ABl_in;
  float* y = ish ? yh : yl;
  int L = ish ? NN : MM;
  int lb = ish ? cbid : cbid - 512;
  int tid = lb * 256 + threadIdx.x;
  int g = tid / (BB * L);                    // uniform per block
  int i = tid % (BB * L);
  int b = i / L, n = i % L;
  const float* xp = x + (size_t)b * CIN * L + n;
  float acc[16];
#pragma unroll
  for (int oo = 0; oo < 16; oo++) acc[oo] = bias[g * 16 + oo];
#pragma unroll
  for (int ch = 0; ch < (CIN + 15) / 16; ch++) {
    float xr[16];
#pragma unroll
    for (int cc = 0; cc < 16; cc++) {
      int c = ch * 16 + cc;
      if (c < CIN) {
        float v = xp[(size_t)c * L];
        if (ABi) v = fmaxf(fmaf(v, ABi[c], ABi[CIN + c]), 0.f);
        xr[cc] = v;
      }
    }
#pragma unroll
    for (int oo = 0; oo < 16; oo++) {
      int o = g * 16 + oo;
#pragma unroll
      for (int cc = 0; cc < 16; cc++) {
        int c = ch * 16 + cc;
        if (c < CIN) acc[oo] = fmaf(W[(size_t)o * CIN + c], xr[cc], acc[oo]);
      }
    }
  }
#pragma unroll
  for (int oo = 0; oo < 16; oo++)
    y[((size_t)b * CQ + g * 16 + oo) * L + n] = acc[oo];
  // block stats reduce via LDS
#pragma unroll
  for (int oo = 0; oo < 16; oo++) red[oo * 257 + threadIdx.x] = acc[oo];
  __syncthreads();
  float* r2 = red + 16 * 257;
  int t = threadIdx.x;
  if (t < 128) {
    int oo = t >> 3, seg = t & 7;
    float s = 0.f, ss = 0.f;
    for (int j = seg * 32; j < seg * 32 + 32; j++) {
      float v = red[oo * 257 + j]; s += v; ss += v * v;
    }
    r2[(oo * 8 + seg) * 2] = s; r2[(oo * 8 + seg) * 2 + 1] = ss;
  }
  __syncthreads();
  if (t < 16) {
    double s = 0.0, ss = 0.0;
    for (int j = 0; j < 8; j++) { s += r2[(t * 8 + j) * 2]; ss += r2[(t * 8 + j) * 2 + 1]; }
    int c = g * 16 + t;
    int base = ish ? 0 : 128;
    atomicAdd(&sums[base + c], s);
    atomicAdd(&sums[base + 64 + c], ss);
  }
  __syncthreads();
  if (t == 0) {
    __threadfence();
    int old = atomicAdd(ctr, 1);
    *plastf = (old == 640 - 1) ? 1 : 0;
  }
  __syncthreads();
  if (*plastf && t < 128) {
    bool fh = t < 64;
    int c = fh ? t : t - 64;
    int base = fh ? 0 : 128;
    double S  = atomicAdd(&sums[base + c], 0.0);
    double SS = atomicAdd(&sums[base + 64 + c], 0.0);
    double nn2 = (double)BB * (fh ? NN : MM);
    double mean = S / nn2, var = SS / nn2 - mean * mean;
    double A = (double)gw[c] / sqrt(var + EPSV);
    float* ABo = fh ? ABh_out : ABl_out;
    ABo[c] = (float)A;
    ABo[64 + c] = (float)((double)btw[c] - mean * A);
  }
}

// ---------------- K2: knnA (blocks 0..1023)  ||  conv1+stats (blocks 1024..1663) ----------------
__global__ __launch_bounds__(256) void k2_k(const float* __restrict__ xyz_hr,
    const float* __restrict__ xyzT, float* __restrict__ theta,
    const float* __restrict__ feat_hr, const float* __restrict__ feat_lr,
    const float* __restrict__ w1, const float* __restrict__ b1,
    double* __restrict__ sums, int* __restrict__ ctr,
    const float* __restrict__ gw, const float* __restrict__ btw,
    float* __restrict__ t1h, float* __restrict__ t1l,
    float* __restrict__ AB1h, float* __restrict__ AB1l)
{
  __shared__ __align__(16) float smem[16 * 257 + 256];
  __shared__ int lastf;
  if (blockIdx.x < 1024) {
    knnA_body(blockIdx.x * 256 + threadIdx.x, xyz_hr, xyzT, theta);
  } else {
    convstats_hl<GEOC>(blockIdx.x - 1024, feat_hr, feat_lr, w1, b1, nullptr, nullptr,
                       t1h, t1l, sums, ctr, gw, btw, AB1h, AB1l, smem, &lastf);
  }
}

// ---- knnC body: 8 queries/wave, 32/block; collect idx (d<th; ties==th by asc idx) + moments ----
__device__ __forceinline__ void knnC_body(int cbid, const float* __restrict__ xyz_hr,
    const float* __restrict__ xyzT, const float* __restrict__ theta,
    int* __restrict__ idx_out, double* __restrict__ mompart, float* smemf)
{
#pragma clang fp contract(off)
  int* s_clt = (int*)smemf;            // 32
  int* s_ceq = s_clt + 32;             // 32
  int* s_lt  = s_ceq + 32;             // 32*16
  int* s_eq  = s_lt + 512;             // 32*64
  int* s_sel = s_eq + 2048;            // 32*16
  float* s_mom = (float*)(s_sel + 512);// 4*9
  int w = threadIdx.x >> 6, l = threadIdx.x & 63;
  int qblk = cbid * 32;
  int b = qblk / NN;
  int n0 = qblk % NN + w * 8;
  if (threadIdx.x < 32) { s_clt[threadIdx.x] = 0; s_ceq[threadIdx.x] = 0; }
  __syncthreads();
  float qx[8], qy[8], qz[8], qs[8], th[8];
#pragma unroll
  for (int q = 0; q < 8; q++) {
    qx[q] = xyz_hr[(b * 3 + 0) * NN + n0 + q];
    qy[q] = xyz_hr[(b * 3 + 1) * NN + n0 + q];
    qz[q] = xyz_hr[(b * 3 + 2) * NN + n0 + q];
    qs[q] = (qx[q] * qx[q] + qy[q] * qy[q]) + qz[q] * qz[q];
    th[q] = theta[(size_t)b * NN + n0 + q];
  }
  const float4* __restrict__ P = ((const float4*)xyzT) + (size_t)b * MM;
  for (int j = 0; j < MM / 64; j++) {
    int m = j * 64 + l;
    float4 p = P[m];
#pragma unroll
    for (int q = 0; q < 8; q++) {
      float d = (qs[q] + p.w) - 2.0f * ((qx[q] * p.x + qy[q] * p.y) + qz[q] * p.z);
      int qq = w * 8 + q;
      if (d < th[q]) {
        int pos = atomicAdd(&s_clt[qq], 1);
        if (pos < 16) s_lt[qq * 16 + pos] = m;
      } else if (d == th[q]) {
        int pos = atomicAdd(&s_ceq[qq], 1);
        if (pos < 64) s_eq[qq * 64 + pos] = m;
      }
    }
  }
  __syncthreads();
  if (threadIdx.x < 32) {
    int qq = threadIdx.x;
    int clt = s_clt[qq]; if (clt > 16) clt = 16;
    int ceq = s_ceq[qq]; if (ceq > 64) ceq = 64;
    for (int j = 0; j < clt; j++) s_sel[qq * 16 + j] = s_lt[qq * 16 + j];
    int need = KK - clt;
    for (int t = 0; t < need; t++) {
      int best = 0x7fffffff, bp = 0;
      for (int j = 0; j < ceq; j++) { int v = s_eq[qq * 64 + j]; if (v < best) { best = v; bp = j; } }
      s_sel[qq * 16 + clt + t] = best;
      s_eq[qq * 64 + bp] = 0x7fffffff;
    }
    size_t base = ((size_t)qblk + qq) * KK;
    for (int j = 0; j < KK; j++) idx_out[base + j] = s_sel[qq * 16 + j];
  }
  __syncthreads();
  float t9[9];
#pragma unroll
  for (int j = 0; j < 9; j++) t9[j] = 0.f;
  for (int slot = threadIdx.x; slot < 512; slot += 256) {
    int qq = slot >> 4, jj = slot & 15;
    int nn_ = qblk % NN + qq;
    float ax = xyz_hr[(b * 3 + 0) * NN + nn_];
    float ay = xyz_hr[(b * 3 + 1) * NN + nn_];
    float az = xyz_hr[(b * 3 + 2) * NN + nn_];
    float4 p = P[s_sel[qq * 16 + jj]];
    float rx = ax - p.x, ry = ay - p.y, rz = az - p.z;
    t9[0] += rx; t9[1] += ry; t9[2] += rz;
    t9[3] += rx * rx; t9[4] += ry * ry; t9[5] += rz * rz;
    t9[6] += rx * ry; t9[7] += rx * rz; t9[8] += ry * rz;
  }
#pragma unroll
  for (int j = 0; j < 9; j++)
    for (int o = 32; o >= 1; o >>= 1) t9[j] += __shfl_down(t9[j], o);
  if (l == 0) { for (int j = 0; j < 9; j++) s_mom[w * 9 + j] = t9[j]; }
  __syncthreads();
  if (threadIdx.x == 0) {
    double* op = mompart + (size_t)cbid * 9;
    for (int j = 0; j < 9; j++)
      op[j] = (double)s_mom[j] + (double)s_mom[9 + j] + (double)s_mom[18 + j] + (double)s_mom[27 + j];
  }
}

// ---------------- K3: knnC (blocks 0..1023)  ||  conv2+stats (blocks 1024..1663) ----------------
__global__ __launch_bounds__(256) void k3_k(const float* __restrict__ xyz_hr,
    const float* __restrict__ xyzT, const float* __restrict__ theta,
    int* __restrict__ idxb, double* __restrict__ mompart,
    const float* __restrict__ t1h, const float* __restrict__ t1l,
    const float* __restrict__ w2, const float* __restrict__ b2,
    const float* __restrict__ AB1h, const float* __restrict__ AB1l,
    double* __restrict__ sums, int* __restrict__ ctr,
    const float* __restrict__ gw, const float* __restrict__ btw,
    float* __restrict__ t2h, float* __restrict__ t2l,
    float* __restrict__ AB2h, float* __restrict__ AB2l)
{
  __shared__ __align__(16) float smem[16 * 257 + 256];
  __shared__ int lastf;
  if (blockIdx.x < 1024) {
    knnC_body(blockIdx.x, xyz_hr, xyzT, theta, idxb, mompart, smem);
  } else {
    convstats_hl<CQ>(blockIdx.x - 1024, t1h, t1l, w2, b2, AB1h, AB1l,
                     t2h, t2l, sums, ctr, gw, btw, AB2h, AB2l, smem, &lastf);
  }
}

// ---- mom2 body: reduce 1024 partials, finalize AB2d ----
__device__ __forceinline__ void mom2_body(const double* __restrict__ part, int nblk,
    const float* __restrict__ w1, const float* __restrict__ b1,
    const float* __restrict__ g, const float* __restrict__ bt, float* __restrict__ AB,
    float* smemf)
{
  double* sh = (double*)smemf;        // 4*9
  double* mo = sh + 36;               // 9
  double acc[9];
#pragma unroll
  for (int j = 0; j < 9; j++) acc[j] = 0.0;
  for (int blk = threadIdx.x; blk < nblk; blk += 256) {
    const double* p = part + (size_t)blk * 9;
#pragma unroll
    for (int j = 0; j < 9; j++) acc[j] += p[j];
  }
#pragma unroll
  for (int j = 0; j < 9; j++)
    for (int o = 32; o >= 1; o >>= 1) acc[j] += __shfl_down(acc[j], o);
  int w = threadIdx.x >> 6, l = threadIdx.x & 63;
  if (l == 0) { for (int j = 0; j < 9; j++) sh[w * 9 + j] = acc[j]; }
  __syncthreads();
  if (threadIdx.x == 0) {
    for (int j = 0; j < 9; j++) mo[j] = sh[j] + sh[9 + j] + sh[18 + j] + sh[27 + j];
  }
  __syncthreads();
  if (threadIdx.x < CQ) {
    int c = threadIdx.x;
    double cnt = (double)BB * NN * KK;
    double mx = mo[0]/cnt, my = mo[1]/cnt, mz = mo[2]/cnt;
    double cxx = mo[3]/cnt - mx*mx, cyy = mo[4]/cnt - my*my, czz = mo[5]/cnt - mz*mz;
    double cxy = mo[6]/cnt - mx*my, cxz = mo[7]/cnt - mx*mz, cyz = mo[8]/cnt - my*mz;
    double wx = w1[c*3], wy = w1[c*3+1], wz = w1[c*3+2];
    double mean = wx*mx + wy*my + wz*mz + (double)b1[c];
    double var = wx*wx*cxx + wy*wy*cyy + wz*wz*czz + 2.0*(wx*wy*cxy + wx*wz*cxz + wy*wz*cyz);
    double A = (double)g[c] / sqrt(var + EPSV);
    AB[c] = (float)A;
    AB[CQ + c] = (float)((double)bt[c] - mean * A);
  }
}

// ---- fk body: fused FiLM + K-conv, CHANNEL-CHUNKED (film recomputed per chunk element) ----
__device__ __forceinline__ void fk_body(int fb, const float* __restrict__ t2l,
    const float* __restrict__ ABl, const float* __restrict__ val,
    const float* __restrict__ scw, const float* __restrict__ scb,
    const float* __restrict__ shw, const float* __restrict__ shb,
    const float* __restrict__ kw, const float* __restrict__ kb,
    float* __restrict__ KfT)
{
  int tid = fb * 256 + threadIdx.x;  // B*M*4
  int g = tid & 3;
  int i = tid >> 2;                  // b*M + m
  int b = i / MM, m = i % MM;
  float v6[6];
#pragma unroll
  for (int j = 0; j < 6; j++) v6[j] = val[((size_t)b * 6 + j) * MM + m];
  float acc[16];
#pragma unroll
  for (int oo = 0; oo < 16; oo++) acc[oo] = kb[g * 16 + oo];
#pragma unroll
  for (int ch = 0; ch < 4; ch++) {
    float xr[16];
#pragma unroll
    for (int cc = 0; cc < 16; cc++) {
      int c = ch * 16 + cc;
      float gv = fmaxf(fmaf(t2l[((size_t)b * CQ + c) * MM + m], ABl[c], ABl[CQ + c]), 0.f);
      float sc = scb[c], sh = shb[c];
#pragma unroll
      for (int j = 0; j < 6; j++) {
        sc = fmaf(scw[c * 6 + j], v6[j], sc);
        sh = fmaf(shw[c * 6 + j], v6[j], sh);
      }
      xr[cc] = fmaf(gv, 1.f + sc, sh);
    }
#pragma unroll
    for (int oo = 0; oo < 16; oo++) {
      int o = g * 16 + oo;
#pragma unroll
      for (int cc = 0; cc < 16; cc++)
        acc[oo] = fmaf(kw[o * CQ + ch * 16 + cc], xr[cc], acc[oo]);
    }
  }
#pragma unroll
  for (int oo = 0; oo < 16; oo++)
    KfT[(size_t)i * CQ + g * 16 + oo] = acc[oo];
}

// ---- convbqq body + stats on tb channels (g<2), CHANNEL-CHUNKED ----
__device__ __forceinline__ void convbqq_body(int cb, const float* __restrict__ x,
    const float* __restrict__ bw, const float* __restrict__ bb,
    const float* __restrict__ Wq, const float* __restrict__ bq,
    const float* __restrict__ R, const float* __restrict__ rb,
    const float* __restrict__ AB, float* __restrict__ tb,
    float* __restrict__ Q, float* __restrict__ Qp,
    double* __restrict__ sums, int* __restrict__ ctr,
    const float* __restrict__ gw, const float* __restrict__ btw,
    float* __restrict__ ABb, float* red, int* plastf)
{
  int tid = cb * 256 + threadIdx.x;  // 10 * B*NN
  int g = tid / (BB * NN);           // uniform per block
  int i = tid % (BB * NN);
  int b = i / NN, n = i % NN;
  const float* xp = x + (size_t)b * CQ * NN + n;
  const float* W; const float* bias; float* y; int o0; int COUTL;
  if (g < 2)      { W = bw; bias = bb; y = tb; o0 = g * 16;       COUTL = 32; }
  else if (g < 6) { W = Wq; bias = bq; y = Q;  o0 = (g - 2) * 16; COUTL = CQ; }
  else            { W = R;  bias = rb; y = Qp; o0 = (g - 6) * 16; COUTL = CQ; }
  float acc[16];
#pragma unroll
  for (int oo = 0; oo < 16; oo++) acc[oo] = bias[o0 + oo];
#pragma unroll
  for (int ch = 0; ch < 4; ch++) {
    float xr[16];
#pragma unroll
    for (int cc = 0; cc < 16; cc++) {
      int c = ch * 16 + cc;
      xr[cc] = fmaxf(fmaf(xp[(size_t)c * NN], AB[c], AB[CQ + c]), 0.f);
    }
#pragma unroll
    for (int oo = 0; oo < 16; oo++) {
#pragma unroll
      for (int cc = 0; cc < 16; cc++)
        acc[oo] = fmaf(W[(o0 + oo) * CQ + ch * 16 + cc], xr[cc], acc[oo]);
    }
  }
#pragma unroll
  for (int oo = 0; oo < 16; oo++)
    y[((size_t)b * COUTL + o0 + oo) * NN + n] = acc[oo];
  if (g >= 2) return;
  // stats on boundary-head pre-activations
#pragma unroll
  for (int oo = 0; oo < 16; oo++) red[oo * 257 + threadIdx.x] = acc[oo];
  __syncthreads();
  float* r2 = red + 16 * 257;
  int t = threadIdx.x;
  if (t < 128) {
    int oo = t >> 3, seg = t & 7;
    float s = 0.f, ss = 0.f;
    for (int j = seg * 32; j < seg * 32 + 32; j++) {
      float v = red[oo * 257 + j]; s += v; ss += v * v;
    }
    r2[(oo * 8 + seg) * 2] = s; r2[(oo * 8 + seg) * 2 + 1] = ss;
  }
  __syncthreads();
  if (t < 16) {
    double s = 0.0, ss = 0.0;
    for (int j = 0; j < 8; j++) { s += r2[(t * 8 + j) * 2]; ss += r2[(t * 8 + j) * 2 + 1]; }
    int c = g * 16 + t;
    atomicAdd(&sums[c], s);
    atomicAdd(&sums[32 + c], ss);
  }
  __syncthreads();
  if (t == 0) {
    __threadfence();
    int old = atomicAdd(ctr, 1);
    *plastf = (old == 256 - 1) ? 1 : 0;
  }
  __syncthreads();
  if (*plastf && t < 32) {
    int c = t;
    double S  = atomicAdd(&sums[c], 0.0);
    double SS = atomicAdd(&sums[32 + c], 0.0);
    double nn2 = (double)BB * NN;
    double mean = S / nn2, var = SS / nn2 - mean * mean;
    double A = (double)gw[c] / sqrt(var + EPSV);
    ABb[c] = (float)A;
    ABb[32 + c] = (float)((double)btw[c] - mean * A);
  }
}

// ---------------- K4: mom2 (block 0) || fk (1..128) || convbqq+stats (129..1408) ----------------
__global__ __launch_bounds__(256) void k4_k(
    const double* __restrict__ mompart,
    const float* __restrict__ rp_w1, const float* __restrict__ rp_b1,
    const float* __restrict__ rp_g, const float* __restrict__ rp_bt, float* __restrict__ AB2d,
    const float* __restrict__ t2l, const float* __restrict__ AB2l, const float* __restrict__ val,
    const float* __restrict__ scw, const float* __restrict__ scb,
    const float* __restrict__ shw, const float* __restrict__ shb,
    const float* __restrict__ kw, const float* __restrict__ kb, float* __restrict__ KfT,
    const float* __restrict__ t2h, const float* __restrict__ bw, const float* __restrict__ bb,
    const float* __restrict__ Wq, const float* __restrict__ bq,
    const float* __restrict__ R, const float* __restrict__ rb,
    const float* __restrict__ AB2h, float* __restrict__ tb,
    float* __restrict__ Q, float* __restrict__ Qp,
    double* __restrict__ sums3, int* __restrict__ ctr3,
    const float* __restrict__ bh_g, const float* __restrict__ bh_bt, float* __restrict__ ABb)
{
  __shared__ __align__(16) float smem[16 * 257 + 256];
  __shared__ int lastf;
  if (blockIdx.x == 0) {
    mom2_body(mompart, 1024, rp_w1, rp_b1, rp_g, rp_bt, AB2d, smem);
  } else if (blockIdx.x <= 128) {
    fk_body(blockIdx.x - 1, t2l, AB2l, val, scw, scb, shw, shb, kw, kb, KfT);
  } else {
    convbqq_body(blockIdx.x - 129, t2h, bw, bb, Wq, bq, R, rb, AB2h, tb, Q, Qp,
                 sums3, ctr3, bh_g, bh_bt, ABb, smem, &lastf);
  }
}

// ---------------- K5: fused pos-enc + attention + output (+ boundary head blocks) ----------------
__global__ __launch_bounds__(256) void attn_k(
    const float* __restrict__ Q, const float* __restrict__ Qp,
    const float* __restrict__ KfT, const int* __restrict__ idxb,
    const float* __restrict__ xyzT, const float* __restrict__ valT,
    const float* __restrict__ xyz_hr, const float* __restrict__ AB,
    const float* __restrict__ w1, const float* __restrict__ b1,
    const float* __restrict__ b2, float* __restrict__ out,
    const float* __restrict__ tb, const float* __restrict__ ABb,
    const float* __restrict__ bhw2, const float* __restrict__ bhb2)
{
  __shared__ float q_s[CQ * 16], qp_s[CQ * 16];
  if (blockIdx.x >= 2048) {
    int i = (blockIdx.x - 2048) * 256 + threadIdx.x;  // B*N
    int b = i / NN, n = i % NN;
    float acc = bhb2[0];
#pragma unroll
    for (int c = 0; c < 32; c++) {
      float v = tb[((size_t)b * 32 + c) * NN + n];
      v = fmaxf(fmaf(v, ABb[c], ABb[32 + c]), 0.f);
      acc = fmaf(bhw2[c], v, acc);
    }
    out[(size_t)BB * 6 * NN + i] = 1.f / (1.f + expf(-acc));
    return;
  }
  const int ngrp = NN / 16;
  int b = blockIdx.x / ngrp;
  int n0 = (blockIdx.x % ngrp) * 16;
  for (int t = threadIdx.x; t < CQ * 16; t += 256) {
    int c = t >> 4, j = t & 15;
    q_s[t]  = Q [((size_t)b * CQ + c) * NN + n0 + j];
    qp_s[t] = Qp[((size_t)b * CQ + c) * NN + n0 + j];
  }
  __syncthreads();
  int q = threadIdx.x >> 4, k = threadIdx.x & 15;
  int n = n0 + q;
  int id = idxb[((size_t)b * NN + n) * KK + k];
  float ax = xyz_hr[(b * 3 + 0) * NN + n];
  float ay = xyz_hr[(b * 3 + 1) * NN + n];
  float az = xyz_hr[(b * 3 + 2) * NN + n];
  float4 pl = ((const float4*)xyzT)[(size_t)b * MM + id];
  float rx = ax - pl.x, ry = ay - pl.y, rz = az - pl.z;
  const float4* kg = (const float4*)(KfT + ((size_t)b * MM + id) * CQ);
  float s = 0.f;
#pragma unroll
  for (int c4 = 0; c4 < CQ / 4; c4++) {
    float4 g4 = kg[c4];
    float ga[4] = {g4.x, g4.y, g4.z, g4.w};
#pragma unroll
    for (int u = 0; u < 4; u++) {
      int c = 4 * c4 + u;
      float t0 = fmaf(w1[c * 3 + 0], rx, fmaf(w1[c * 3 + 1], ry, w1[c * 3 + 2] * rz)) + b1[c];
      float pe = fmaxf(fmaf(t0, AB[c], AB[CQ + c]), 0.f);
      s = fmaf(q_s[c * 16 + q], ga[u] + b2[c], s);
      s = fmaf(qp_s[c * 16 + q], pe, s);
    }
  }
  s *= 0.125f;
  float mx = s;
#pragma unroll
  for (int o = 8; o >= 1; o >>= 1) mx = fmaxf(mx, __shfl_xor(mx, o, 16));
  float p = expf(s - mx);
  float sum = p;
#pragma unroll
  for (int o = 8; o >= 1; o >>= 1) sum += __shfl_xor(sum, o, 16);
  float attn = p / sum;
  const float4* vt = (const float4*)(valT + ((size_t)b * MM + id) * 8);
  float4 va = vt[0], vb = vt[1];
  float oc[6] = {attn*va.x, attn*va.y, attn*va.z, attn*va.w, attn*vb.x, attn*vb.y};
#pragma unroll
  for (int c = 0; c < 6; c++) {
    float a = oc[c];
#pragma unroll
    for (int o = 8; o >= 1; o >>= 1) a += __shfl_xor(a, o, 16);
    oc[c] = a;
  }
  if (k == 0) {
#pragma unroll
    for (int c = 0; c < 6; c++) out[((size_t)b * 6 + c) * NN + n] = oc[c];
  }
}

extern "C" void kernel_launch(void* const* d_in, const int* in_sizes, int n_in,
                              void* d_out, int out_size, void* d_ws, size_t ws_size,
                              hipStream_t stream)
{
  const float* xyz_hr = (const float*)d_in[0];
  const float* xyz_lr = (const float*)d_in[1];
  const float* val_lr = (const float*)d_in[2];
  const float* feat_hr= (const float*)d_in[3];
  const float* feat_lr= (const float*)d_in[4];
  const float* ge_w1 = (const float*)d_in[5];
  const float* ge_b1 = (const float*)d_in[6];
  const float* ge_g1 = (const float*)d_in[7];
  const float* ge_bt1= (const float*)d_in[8];
  const float* ge_w2 = (const float*)d_in[9];
  const float* ge_b2 = (const float*)d_in[10];
  const float* ge_g2 = (const float*)d_in[11];
  const float* ge_bt2= (const float*)d_in[12];
  const float* sc_w = (const float*)d_in[13];
  const float* sc_b = (const float*)d_in[14];
  const float* sh_w = (const float*)d_in[15];
  const float* sh_b = (const float*)d_in[16];
  const float* q_w  = (const float*)d_in[17];
  const float* q_b  = (const float*)d_in[18];
  const float* k_w  = (const float*)d_in[19];
  const float* k_b  = (const float*)d_in[20];
  const float* bh_w1= (const float*)d_in[21];
  const float* bh_b1= (const float*)d_in[22];
  const float* bh_g = (const float*)d_in[23];
  const float* bh_bt= (const float*)d_in[24];
  const float* bh_w2= (const float*)d_in[25];
  const float* bh_b2= (const float*)d_in[26];
  const float* rp_w1= (const float*)d_in[27];
  const float* rp_b1= (const float*)d_in[28];
  const float* rp_g = (const float*)d_in[29];
  const float* rp_bt= (const float*)d_in[30];
  const float* rp_w2= (const float*)d_in[31];
  const float* rp_b2= (const float*)d_in[32];
  float* out = (float*)d_out;

  // header (zeroed by init_k): [0,96) pad | ctrs 8 ints | sums 576 dbl
  int*    hdr  = (int*)d_ws;
  int*    ctrs = (int*)((char*)d_ws + 96);
  double* sums = (double*)((char*)d_ws + 128);      // sums1[256] | sums2[256] | sums3[64]
  float*  base = (float*)((char*)d_ws + 5504);
  float* AB1h = base;          // 128
  float* AB2h = base + 128;    // 128
  float* AB1l = base + 256;    // 128
  float* AB2l = base + 384;    // 128
  float* ABb  = base + 512;    // 64
  float* AB2d = base + 576;    // 128
  float* big  = base + 768;
  float* t1_hr = big;                      // 2*64*16384
  float* t2_hr = t1_hr + 2097152;
  float* Qb    = t2_hr + 2097152;
  float* Qp    = Qb    + 2097152;
  float* t1_lr = Qp    + 2097152;          // 2*64*4096
  float* t2_lr = t1_lr + 524288;
  float* Rbuf  = t2_lr + 524288;
  float* KfT   = Rbuf  + 524288;           // [B,M,64]
  float* tb    = KfT   + 524288;           // 2*32*16384
  float* xyzT  = tb    + 1048576;          // [B,M,4]
  float* valT  = xyzT  + 32768;            // [B,M,8]
  int*   idxb  = (int*)(valT + 65536);     // 2*16384*16 ints
  double* mompart = (double*)(idxb + BB * NN * KK);  // 1024*9 dbl (dedicated)
  float* theta = Qb;                       // overlay: consumed in K3, Qb written in K4
  float* Rw    = Rbuf;
  float* rbv   = Rbuf + 4096;

  init_k<<<33, 256, 0, stream>>>(xyz_lr, val_lr, xyzT, valT, q_w, q_b, rp_w2, Rw, rbv, hdr);

  k2_k<<<1664, 256, 0, stream>>>(xyz_hr, xyzT, theta, feat_hr, feat_lr, ge_w1, ge_b1,
                                 sums, ctrs + 0, ge_g1, ge_bt1, t1_hr, t1_lr, AB1h, AB1l);

  k3_k<<<1664, 256, 0, stream>>>(xyz_hr, xyzT, theta, idxb, mompart, t1_hr, t1_lr,
                                 ge_w2, ge_b2, AB1h, AB1l, sums + 256, ctrs + 1,
                                 ge_g2, ge_bt2, t2_hr, t2_lr, AB2h, AB2l);

  k4_k<<<1409, 256, 0, stream>>>(mompart, rp_w1, rp_b1, rp_g, rp_bt, AB2d,
                                 t2_lr, AB2l, val_lr, sc_w, sc_b, sh_w, sh_b, k_w, k_b, KfT,
                                 t2_hr, bh_w1, bh_b1, q_w, q_b, Rw, rbv, AB2h, tb, Qb, Qp,
                                 sums + 512, ctrs + 2, bh_g, bh_bt, ABb);

  attn_k<<<2048 + 128, 256, 0, stream>>>(Qb, Qp, KfT, idxb, xyzT, valT, xyz_hr, AB2d,
                                         rp_w1, rp_b1, rp_b2, out, tb, ABb, bh_w2, bh_b2);
}